// Round 2
// baseline (5109.019 us; speedup 1.0000x reference)
//
#include <hip/hip_runtime.h>
#include <math.h>

#define N_TOTAL    262144
#define NUM_SAMPLE 1024
#define FPS_BLOCKS 64
#define FPS_THREADS 256
#define FPS_PPT (N_TOTAL / (FPS_BLOCKS * FPS_THREADS))   // 16

__device__ __forceinline__ float addrn(float a, float b) { return __fadd_rn(a, b); }
__device__ __forceinline__ float subrn(float a, float b) { return __fsub_rn(a, b); }
__device__ __forceinline__ float mulrn(float a, float b) { return __fmul_rn(a, b); }

// ---------------- LAPACK emulation (f32) ----------------
__device__ __forceinline__ float slapy2f(float x, float y) {
  float xa = fabsf(x), ya = fabsf(y);
  float w = fmaxf(xa, ya), z = fminf(xa, ya);
  if (z == 0.f) return w;
  float t = z / w;
  return w * __fsqrt_rn(1.f + t * t);
}

// LAPACK >= 3.10 slartg convention (mid-range path)
__device__ __forceinline__ void slartgf(float f, float g, float& c, float& s, float& r) {
  if (g == 0.f) { c = 1.f; s = 0.f; r = f; }
  else if (f == 0.f) { c = 0.f; s = (g > 0.f) ? 1.f : -1.f; r = fabsf(g); }
  else {
    float d = __fsqrt_rn(f * f + g * g);
    c = fabsf(f) / d;
    r = (f >= 0.f) ? d : -d;     // sign(d, f)
    s = g / r;
  }
}

__device__ void slaev2f(float a, float b, float c0, float& rt1, float& rt2,
                        float& cs1, float& sn1) {
  float sm = a + c0, df = a - c0;
  float adf = fabsf(df), tb = b + b, ab = fabsf(tb);
  float acmx, acmn;
  if (fabsf(a) > fabsf(c0)) { acmx = a; acmn = c0; } else { acmx = c0; acmn = a; }
  float rt;
  if (adf > ab)      { float t = ab / adf; rt = adf * __fsqrt_rn(1.f + t * t); }
  else if (adf < ab) { float t = adf / ab; rt = ab * __fsqrt_rn(1.f + t * t); }
  else               { rt = ab * __fsqrt_rn(2.f); }
  int sgn1;
  if (sm < 0.f)      { rt1 = 0.5f * (sm - rt); sgn1 = -1; rt2 = (acmx / rt1) * acmn - (b / rt1) * b; }
  else if (sm > 0.f) { rt1 = 0.5f * (sm + rt); sgn1 = 1;  rt2 = (acmx / rt1) * acmn - (b / rt1) * b; }
  else               { rt1 = 0.5f * rt; rt2 = -0.5f * rt; sgn1 = 1; }
  float cs; int sgn2;
  if (df >= 0.f) { cs = df + rt; sgn2 = 1; } else { cs = df - rt; sgn2 = -1; }
  float acs = fabsf(cs);
  if (acs > ab) {
    float ct = -tb / cs;
    sn1 = 1.f / __fsqrt_rn(1.f + ct * ct);
    cs1 = ct * sn1;
  } else {
    if (ab == 0.f) { cs1 = 1.f; sn1 = 0.f; }
    else { float tn = -cs / tb; cs1 = 1.f / __fsqrt_rn(1.f + tn * tn); sn1 = tn * cs1; }
  }
  if (sgn1 == sgn2) { float tn = cs1; cs1 = -sn1; sn1 = tn; }
}

#define D_(i) d[(i)-1]
#define E_(i) e[(i)-1]

__device__ void ssteqr3(float d[3], float e[2], float Z[3][3]) {
  const float eps    = 5.9604645e-08f;   // slamch('E') single
  const float eps2   = 3.5527137e-15f;
  const float safmin = 1.17549435e-38f;
  const float ssfmax = 3.0744573e+18f;   // sqrt(1/safmin)/3
  const float ssfmin = 3.0517578e-05f;   // sqrt(safmin)/eps^2
  const int n = 3;
  int jtot = 0, nmaxit = 90;
  int l1 = 1;

  while (true) {
    if (l1 > n) break;
    if (l1 > 1) E_(l1 - 1) = 0.f;
    int m = n;
    for (int mm = l1; mm <= n - 1; ++mm) {
      float tst = fabsf(E_(mm));
      if (tst == 0.f) { m = mm; break; }
      if (tst <= (__fsqrt_rn(fabsf(D_(mm))) * __fsqrt_rn(fabsf(D_(mm + 1)))) * eps) {
        E_(mm) = 0.f; m = mm; break;
      }
    }
    int l = l1, lsv = l, lend = m, lendsv = m;
    l1 = m + 1;
    if (lend == l) continue;

    float anorm = fabsf(D_(lend));
    for (int i2 = l; i2 <= lend - 1; ++i2) {
      anorm = fmaxf(anorm, fabsf(D_(i2)));
      anorm = fmaxf(anorm, fabsf(E_(i2)));
    }
    int iscale = 0;
    if (anorm == 0.f) continue;
    if (anorm > ssfmax) {
      iscale = 1; float mul = ssfmax / anorm;
      for (int i2 = l; i2 <= lend; ++i2) D_(i2) *= mul;
      for (int i2 = l; i2 <= lend - 1; ++i2) E_(i2) *= mul;
    } else if (anorm < ssfmin) {
      iscale = 2; float mul = ssfmin / anorm;
      for (int i2 = l; i2 <= lend; ++i2) D_(i2) *= mul;
      for (int i2 = l; i2 <= lend - 1; ++i2) E_(i2) *= mul;
    }

    if (fabsf(D_(lend)) < fabsf(D_(l))) { int t = l; l = lend; lend = t; }

    if (lend > l) {
      // ---- QL ----
      while (true) {
        int m2 = lend;
        if (l != lend) {
          for (int mm = l; mm <= lend - 1; ++mm) {
            float tst = fabsf(E_(mm)); tst = tst * tst;
            if (tst <= (eps2 * fabsf(D_(mm))) * fabsf(D_(mm + 1)) + safmin) { m2 = mm; break; }
          }
        }
        if (m2 < lend) E_(m2) = 0.f;
        float p = D_(l);
        if (m2 == l) { D_(l) = p; l = l + 1; if (l <= lend) continue; break; }
        if (m2 == l + 1) {
          float rt1, rt2, cc, ss;
          slaev2f(D_(l), E_(l), D_(l + 1), rt1, rt2, cc, ss);
          for (int i2 = 0; i2 < 3; ++i2) {
            float tmp = Z[i2][l];                 // col (l+1) 1-based
            Z[i2][l]     = cc * tmp - ss * Z[i2][l - 1];
            Z[i2][l - 1] = ss * tmp + cc * Z[i2][l - 1];
          }
          D_(l) = rt1; D_(l + 1) = rt2; E_(l) = 0.f;
          l = l + 2; if (l <= lend) continue; break;
        }
        if (jtot == nmaxit) break;
        ++jtot;
        float g = (D_(l + 1) - p) / (2.f * E_(l));
        float r = slapy2f(g, 1.f);
        float sgn_rg = (g >= 0.f) ? r : -r;
        g = D_(m2) - p + E_(l) / (g + sgn_rg);
        float s = 1.f, c = 1.f;
        p = 0.f;
        float csv[2], ssv[2];
        for (int i2 = m2 - 1; i2 >= l; --i2) {
          float f = s * E_(i2);
          float b = c * E_(i2);
          slartgf(g, f, c, s, r);
          if (i2 != m2 - 1) E_(i2 + 1) = r;
          g = D_(i2 + 1) - p;
          r = (D_(i2) - g) * s + 2.f * c * b;
          p = s * r;
          D_(i2 + 1) = g + p;
          g = c * r - b;
          csv[i2 - l] = c; ssv[i2 - l] = -s;
        }
        for (int j = m2 - 1; j >= l; --j) {
          float ct = csv[j - l], st = ssv[j - l];
          for (int i2 = 0; i2 < 3; ++i2) {
            float tmp = Z[i2][j];
            Z[i2][j]     = ct * tmp - st * Z[i2][j - 1];
            Z[i2][j - 1] = st * tmp + ct * Z[i2][j - 1];
          }
        }
        D_(l) = D_(l) - p;
        E_(l) = g;
      }
    } else {
      // ---- QR ----
      while (true) {
        int m2 = lend;
        if (l != lend) {
          for (int mm = l; mm >= lend + 1; --mm) {
            float tst = fabsf(E_(mm - 1)); tst = tst * tst;
            if (tst <= (eps2 * fabsf(D_(mm))) * fabsf(D_(mm - 1)) + safmin) { m2 = mm; break; }
          }
        }
        if (m2 > lend) E_(m2 - 1) = 0.f;
        float p = D_(l);
        if (m2 == l) { D_(l) = p; l = l - 1; if (l >= lend) continue; break; }
        if (m2 == l - 1) {
          float rt1, rt2, cc, ss;
          slaev2f(D_(l - 1), E_(l - 1), D_(l), rt1, rt2, cc, ss);
          for (int i2 = 0; i2 < 3; ++i2) {
            float tmp = Z[i2][l - 1];             // col l 1-based
            Z[i2][l - 1] = cc * tmp - ss * Z[i2][l - 2];
            Z[i2][l - 2] = ss * tmp + cc * Z[i2][l - 2];
          }
          D_(l - 1) = rt1; D_(l) = rt2; E_(l - 1) = 0.f;
          l = l - 2; if (l >= lend) continue; break;
        }
        if (jtot == nmaxit) break;
        ++jtot;
        float g = (D_(l - 1) - p) / (2.f * E_(l - 1));
        float r = slapy2f(g, 1.f);
        float sgn_rg = (g >= 0.f) ? r : -r;
        g = D_(m2) - p + E_(l - 1) / (g + sgn_rg);
        float s = 1.f, c = 1.f;
        p = 0.f;
        float csv[2], ssv[2];
        for (int i2 = m2; i2 <= l - 1; ++i2) {
          float f = s * E_(i2);
          float b = c * E_(i2);
          slartgf(g, f, c, s, r);
          if (i2 != m2) E_(i2 - 1) = r;
          g = D_(i2) - p;
          r = (D_(i2 + 1) - g) * s + 2.f * c * b;
          p = s * r;
          D_(i2) = g + p;
          g = c * r - b;
          csv[i2 - m2] = c; ssv[i2 - m2] = s;
        }
        for (int j = m2; j <= l - 1; ++j) {
          float ct = csv[j - m2], st = ssv[j - m2];
          for (int i2 = 0; i2 < 3; ++i2) {
            float tmp = Z[i2][j];
            Z[i2][j]     = ct * tmp - st * Z[i2][j - 1];
            Z[i2][j - 1] = st * tmp + ct * Z[i2][j - 1];
          }
        }
        D_(l) = D_(l) - p;
        E_(l - 1) = g;
      }
    }
    if (iscale == 1) {
      float mul = anorm / ssfmax;
      for (int i2 = lsv; i2 <= lendsv; ++i2) D_(i2) *= mul;
      for (int i2 = lsv; i2 <= lendsv - 1; ++i2) E_(i2) *= mul;
    } else if (iscale == 2) {
      float mul = anorm / ssfmin;
      for (int i2 = lsv; i2 <= lendsv; ++i2) D_(i2) *= mul;
      for (int i2 = lsv; i2 <= lendsv - 1; ++i2) E_(i2) *= mul;
    }
  }
  // selection sort ascending, swap eigenvector columns (as LAPACK)
  for (int ii = 2; ii <= n; ++ii) {
    int i2 = ii - 1, k = i2;
    float p = D_(i2);
    for (int j = ii; j <= n; ++j) if (D_(j) < p) { k = j; p = D_(j); }
    if (k != i2) {
      D_(k) = D_(i2); D_(i2) = p;
      for (int rr = 0; rr < 3; ++rr) {
        float t = Z[rr][i2 - 1]; Z[rr][i2 - 1] = Z[rr][k - 1]; Z[rr][k - 1] = t;
      }
    }
  }
}

// full ssyevd path for 3x3 (lower): ssytrd -> ssteqr -> sormtr; returns column 0
__device__ void eigh3_smallest(float a00, float a10, float a20, float a11, float a21, float a22,
                               float& nx, float& ny, float& nz) {
  float d[3], e[2];
  float Z[3][3] = {{1.f,0.f,0.f},{0.f,1.f,0.f},{0.f,0.f,1.f}};
  float tau, v2;
  {
    float alpha = a10, x = a20;
    float xnorm = fabsf(x);
    if (xnorm == 0.f) {
      tau = 0.f; v2 = 0.f;
      d[0] = a00; d[1] = a11; d[2] = a22;
      e[0] = alpha; e[1] = a21;
    } else {
      float beta = -copysignf(slapy2f(alpha, x), alpha);
      tau = (beta - alpha) / beta;
      v2 = x / (alpha - beta);
      // w = tau * A22 * v   (ssymv lower order)
      float w0 = (tau * a11) + tau * (a21 * v2);
      float w1 = (tau * a21) + (tau * v2) * a22;
      float ac = (-0.5f * tau) * (w0 + w1 * v2);
      w0 = w0 + ac;
      w1 = w1 + ac * v2;
      d[0] = a00;
      d[1] = (a11 - w0) - w0;            // dsyr2 order
      d[2] = (a22 - v2 * w1) - w1 * v2;
      e[0] = beta;
      e[1] = (a21 - v2 * w0) - w1;
    }
  }
  ssteqr3(d, e, Z);
  if (tau != 0.f) {   // sormtr: Z := H1 * Z
    for (int c = 0; c < 3; ++c) {
      float w = Z[1][c] + Z[2][c] * v2;
      float temp = (-tau) * w;
      Z[1][c] = Z[1][c] + temp;
      Z[2][c] = Z[2][c] + v2 * temp;
    }
  }
  nx = Z[0][0]; ny = Z[1][0]; nz = Z[2][0];
}

// ---------------- K0: init workspace ----------------
__global__ void k0_init(unsigned long long* slots, int* sample_idx) {
  int t = blockIdx.x * blockDim.x + threadIdx.x;
  if (t < 2 * FPS_BLOCKS) slots[t] = 0ull;   // both ping-pong sets
  if (t == 0) sample_idx[0] = 0;
}

// ---------------- K1: farthest point sampling (persistent, 1023 steps) ----------------
// Flat all-to-all barrier: block b publishes its partial best (key | step-tag)
// to slots[set][b] (own cacheline, no RMW contention); wave 0 of every block
// polls all 64 slots (lane i -> slot i), butterfly-reduces, proceeds.
// Ping-pong sets + 10-bit step tag make reuse safe (a block can be at most
// one step ahead, because publishing step s+1 requires completing the poll of
// step s, and overwriting a set requires two publishes).
__global__ __launch_bounds__(FPS_THREADS) void k1_fps(
    const float* __restrict__ pos,
    unsigned long long* __restrict__ slots,
    int* __restrict__ sample_idx) {
  __shared__ unsigned long long wbest[FPS_THREADS / 64];
  __shared__ int sh_widx;
  const int tid = blockIdx.x * FPS_THREADS + threadIdx.x;
  float px[FPS_PPT], py[FPS_PPT], pz[FPS_PPT], md[FPS_PPT];
#pragma unroll
  for (int k = 0; k < FPS_PPT; ++k) {
    int p = tid + k * (FPS_BLOCKS * FPS_THREADS);
    px[k] = pos[3 * p]; py[k] = pos[3 * p + 1]; pz[k] = pos[3 * p + 2];
    md[k] = 1e10f;
  }
  int last = 0;
  for (int s = 0; s < NUM_SAMPLE - 1; ++s) {
    float lx = pos[3 * last], ly = pos[3 * last + 1], lz = pos[3 * last + 2];
    unsigned long long best = 0ull;
#pragma unroll
    for (int k = 0; k < FPS_PPT; ++k) {
      float dx = subrn(px[k], lx), dy = subrn(py[k], ly), dz = subrn(pz[k], lz);
      float d2 = addrn(addrn(mulrn(dx, dx), mulrn(dy, dy)), mulrn(dz, dz));
      float m = fminf(md[k], d2);
      md[k] = m;
      // key: [63:32]=f32 bits (nonneg -> unsigned order == float order),
      // [31:10]=0x3FFFFF - idx (smaller idx wins ties), [9:0]=step tag (added at publish)
      unsigned long long key =
          ((unsigned long long)__float_as_uint(m) << 32) |
          ((unsigned)(0x3FFFFF - (tid + k * (FPS_BLOCKS * FPS_THREADS))) << 10);
      best = (key > best) ? key : best;
    }
#pragma unroll
    for (int off = 32; off > 0; off >>= 1) {
      unsigned long long o = (unsigned long long)__shfl_down((long long)best, (unsigned)off, 64);
      best = (o > best) ? o : best;
    }
    int lane = threadIdx.x & 63, wv = threadIdx.x >> 6;
    if (lane == 0) wbest[wv] = best;
    __syncthreads();
    if (threadIdx.x < 64) {
      // block-level partial (all 64 lanes compute the same value)
      unsigned long long myb = wbest[0];
#pragma unroll
      for (int w = 1; w < FPS_THREADS / 64; ++w) myb = (wbest[w] > myb) ? wbest[w] : myb;
      const unsigned want = (unsigned)(s + 1);            // 10-bit tag, 1..1023
      unsigned long long* setbase = slots + (size_t)(s & 1) * FPS_BLOCKS;
      if (threadIdx.x == 0)
        __hip_atomic_store(setbase + blockIdx.x, myb | want,
                           __ATOMIC_RELEASE, __HIP_MEMORY_SCOPE_AGENT);
      // lane i polls slot i until it carries this step's tag
      unsigned long long v;
      do {
        v = __hip_atomic_load(setbase + threadIdx.x,
                              __ATOMIC_ACQUIRE, __HIP_MEMORY_SCOPE_AGENT);
      } while ((unsigned)(v & 1023ull) != want);
      // butterfly max: every lane ends with the global winner
#pragma unroll
      for (int mk = 1; mk < 64; mk <<= 1) {
        unsigned long long o = (unsigned long long)__shfl_xor((long long)v, mk, 64);
        v = (o > v) ? o : v;
      }
      int widx = 0x3FFFFF - (int)((v >> 10) & 0x3FFFFFull);
      if (threadIdx.x == 0) {
        sh_widx = widx;
        if (blockIdx.x == 0) sample_idx[s + 1] = widx;
      }
    }
    __syncthreads();
    last = sh_widx;
  }
}

// ---------------- K2: gather samples, KNN normals, MLP, softmax/argmax ----------------
__global__ __launch_bounds__(64) void k2_samples(
    const float* __restrict__ pos, const float* __restrict__ col,
    const float* __restrict__ W1, const float* __restrict__ b1,
    const float* __restrict__ W2, const float* __restrict__ b2,
    const float* __restrict__ W3, const float* __restrict__ b3,
    const int* __restrict__ sample_idx,
    float4* __restrict__ sp4g, float* __restrict__ featd, int* __restrict__ lbl) {
  __shared__ float4 sp[NUM_SAMPLE];
  __shared__ float hbuf[64][129];
  const int tid = threadIdx.x;
  for (int i = tid; i < NUM_SAMPLE; i += 64) {
    int idx = sample_idx[i];
    float x = pos[3 * idx], y = pos[3 * idx + 1], z = pos[3 * idx + 2];
    float nrm = addrn(addrn(mulrn(x, x), mulrn(y, y)), mulrn(z, z));
    float4 v = make_float4(x, y, z, nrm);
    sp[i] = v;
    if (blockIdx.x == 0) sp4g[i] = v;
  }
  __syncthreads();
  const int r = blockIdx.x * 64 + tid;

  // ---- top-17 nearest (stable ascending (d2, idx)) ----
  float bd[17]; int bi[17];
#pragma unroll
  for (int t = 0; t < 17; ++t) { bd[t] = 3.402823466e+38f; bi[t] = -1; }
  float4 pr = sp[r];
  for (int j = 0; j < NUM_SAMPLE; ++j) {
    float4 q = sp[j];
    float dot = fmaf(pr.z, q.z, fmaf(pr.y, q.y, mulrn(pr.x, q.x)));
    float d2 = subrn(addrn(pr.w, q.w), mulrn(2.f, dot));
    if (d2 < bd[16]) {
#pragma unroll
      for (int p = 16; p >= 1; --p) {
        bool a = d2 < bd[p - 1];
        bool bsel = d2 < bd[p];
        float nv = a ? bd[p - 1] : (bsel ? d2 : bd[p]);
        int niv = a ? bi[p - 1] : (bsel ? j : bi[p]);
        bd[p] = nv; bi[p] = niv;
      }
      if (d2 < bd[0]) { bd[0] = d2; bi[0] = j; }
    }
  }

  // ---- mean / covariance over neighbors 1..16 (sorted order) ----
  float mx = 0.f, my = 0.f, mz = 0.f;
#pragma unroll
  for (int k = 1; k <= 16; ++k) {
    float4 q = sp[bi[k]];
    mx = addrn(mx, q.x); my = addrn(my, q.y); mz = addrn(mz, q.z);
  }
  mx = mulrn(mx, 0.0625f); my = mulrn(my, 0.0625f); mz = mulrn(mz, 0.0625f);
  float c00 = 0.f, c01 = 0.f, c02 = 0.f, c11 = 0.f, c12 = 0.f, c22 = 0.f;
#pragma unroll
  for (int k = 1; k <= 16; ++k) {
    float4 q = sp[bi[k]];
    float dx = subrn(q.x, mx), dy = subrn(q.y, my), dz = subrn(q.z, mz);
    c00 = addrn(c00, mulrn(dx, dx)); c01 = addrn(c01, mulrn(dx, dy));
    c02 = addrn(c02, mulrn(dx, dz)); c11 = addrn(c11, mulrn(dy, dy));
    c12 = addrn(c12, mulrn(dy, dz)); c22 = addrn(c22, mulrn(dz, dz));
  }
  c00 /= 15.f; c01 /= 15.f; c02 /= 15.f; c11 /= 15.f; c12 /= 15.f; c22 /= 15.f;

  float n0, n1, n2;
  eigh3_smallest(c00, c01, c02, c11, c12, c22, n0, n1, n2);
  float nn = __fsqrt_rn(addrn(addrn(mulrn(n0, n0), mulrn(n1, n1)), mulrn(n2, n2)));
  float den = addrn(nn, 1e-8f);
  n0 /= den; n1 /= den; n2 /= den;

  // ---- MLP ----
  int myidx = sample_idx[r];
  float f9[9] = { pr.x, pr.y, pr.z,
                  col[3 * myidx], col[3 * myidx + 1], col[3 * myidx + 2],
                  n0, n1, n2 };
  for (int jo = 0; jo < 128; ++jo) {
    float acc = 0.f;
#pragma unroll
    for (int k = 0; k < 9; ++k) acc = fmaf(f9[k], W1[k * 128 + jo], acc);
    acc += b1[jo];
    hbuf[tid][jo] = fmaxf(acc, 0.f);
  }
  float pd[13];
#pragma unroll
  for (int c = 0; c < 13; ++c) pd[c] = 0.f;
  for (int io = 0; io < 128; io += 16) {
    float acc[16];
#pragma unroll
    for (int t = 0; t < 16; ++t) acc[t] = 0.f;
    for (int j = 0; j < 128; ++j) {
      float hj = hbuf[tid][j];
#pragma unroll
      for (int t = 0; t < 16; ++t) acc[t] = fmaf(hj, W2[j * 128 + io + t], acc[t]);
    }
#pragma unroll
    for (int t = 0; t < 16; ++t) {
      float h2 = fmaxf(acc[t] + b2[io + t], 0.f);
#pragma unroll
      for (int c = 0; c < 13; ++c) pd[c] = fmaf(h2, W3[(io + t) * 13 + c], pd[c]);
    }
  }
#pragma unroll
  for (int c = 0; c < 13; ++c) pd[c] += b3[c];
  float mmax = pd[0];
#pragma unroll
  for (int c = 1; c < 13; ++c) mmax = fmaxf(mmax, pd[c]);
  float es = 0.f, ev[13];
#pragma unroll
  for (int c = 0; c < 13; ++c) { ev[c] = expf(pd[c] - mmax); es += ev[c]; }
#pragma unroll
  for (int c = 0; c < 13; ++c) featd[r * 13 + c] = ev[c] / es;
  int am = 0; float bv = pd[0];
#pragma unroll
  for (int c = 1; c < 13; ++c) { if (pd[c] > bv) { bv = pd[c]; am = c; } }
  lbl[r] = am;
}

// ---------------- K3: nearest sample + gather outputs ----------------
__global__ __launch_bounds__(256) void k3_assign(
    const float* __restrict__ pos,
    const float4* __restrict__ sp4g,
    const float* __restrict__ featd,
    const int* __restrict__ lbl,
    float* __restrict__ out) {
  __shared__ float4 sp[NUM_SAMPLE];
  for (int i = threadIdx.x; i < NUM_SAMPLE; i += 256) sp[i] = sp4g[i];
  __syncthreads();
  int i = blockIdx.x * 256 + threadIdx.x;
  float x = pos[3 * i], y = pos[3 * i + 1], z = pos[3 * i + 2];
  float an = addrn(addrn(mulrn(x, x), mulrn(y, y)), mulrn(z, z));
  float bestd = 3.402823466e+38f; int bestj = 0;
#pragma unroll 4
  for (int j = 0; j < NUM_SAMPLE; ++j) {
    float4 q = sp[j];
    float dot = fmaf(z, q.z, fmaf(y, q.y, mulrn(x, q.x)));
    float d2 = subrn(addrn(an, q.w), mulrn(2.f, dot));
    if (d2 < bestd) { bestd = d2; bestj = j; }
  }
  const float* fr = featd + bestj * 13;
  float* o = out + (size_t)i * 13;
#pragma unroll
  for (int c = 0; c < 13; ++c) o[c] = fr[c];
  out[(size_t)N_TOTAL * 13 + i] = (float)lbl[bestj];
}

extern "C" void kernel_launch(void* const* d_in, const int* in_sizes, int n_in,
                              void* d_out, int out_size, void* d_ws, size_t ws_size,
                              hipStream_t stream) {
  (void)in_sizes; (void)n_in; (void)out_size; (void)ws_size;
  const float* pos = (const float*)d_in[0];
  const float* col = (const float*)d_in[1];
  const float* W1 = (const float*)d_in[2];
  const float* b1 = (const float*)d_in[3];
  const float* W2 = (const float*)d_in[4];
  const float* b2 = (const float*)d_in[5];
  const float* W3 = (const float*)d_in[6];
  const float* b3 = (const float*)d_in[7];
  float* out = (float*)d_out;

  char* w = (char*)d_ws;
  unsigned long long* slots = (unsigned long long*)(w);          //  1 KiB (2 sets x 64)
  int* sample_idx = (int*)(w + 8192);                            //  4 KiB
  float4* sp4g = (float4*)(w + 16384);                           // 16 KiB
  float* featd = (float*)(w + 32768);                            // 52 KiB
  int* lbl = (int*)(w + 32768 + 53248);                          //  4 KiB

  k0_init<<<1, 256, 0, stream>>>(slots, sample_idx);
  k1_fps<<<FPS_BLOCKS, FPS_THREADS, 0, stream>>>(pos, slots, sample_idx);
  k2_samples<<<16, 64, 0, stream>>>(pos, col, W1, b1, W2, b2, W3, b3,
                                    sample_idx, sp4g, featd, lbl);
  k3_assign<<<N_TOTAL / 256, 256, 0, stream>>>(pos, sp4g, featd, lbl, out);
}

// Round 3
// 4933.361 us; speedup vs baseline: 1.0356x; 1.0356x over previous
//
#include <hip/hip_runtime.h>
#include <math.h>

#define N_TOTAL    262144
#define NUM_SAMPLE 1024
#define FPS_BLOCKS 64
#define FPS_THREADS 256
#define FPS_PPT (N_TOTAL / (FPS_BLOCKS * FPS_THREADS))   // 16

__device__ __forceinline__ float addrn(float a, float b) { return __fadd_rn(a, b); }
__device__ __forceinline__ float subrn(float a, float b) { return __fsub_rn(a, b); }
__device__ __forceinline__ float mulrn(float a, float b) { return __fmul_rn(a, b); }

// ---------------- LAPACK emulation (f32) ----------------
__device__ __forceinline__ float slapy2f(float x, float y) {
  float xa = fabsf(x), ya = fabsf(y);
  float w = fmaxf(xa, ya), z = fminf(xa, ya);
  if (z == 0.f) return w;
  float t = z / w;
  return w * __fsqrt_rn(1.f + t * t);
}

// LAPACK >= 3.10 slartg convention (mid-range path)
__device__ __forceinline__ void slartgf(float f, float g, float& c, float& s, float& r) {
  if (g == 0.f) { c = 1.f; s = 0.f; r = f; }
  else if (f == 0.f) { c = 0.f; s = (g > 0.f) ? 1.f : -1.f; r = fabsf(g); }
  else {
    float d = __fsqrt_rn(f * f + g * g);
    c = fabsf(f) / d;
    r = (f >= 0.f) ? d : -d;     // sign(d, f)
    s = g / r;
  }
}

__device__ void slaev2f(float a, float b, float c0, float& rt1, float& rt2,
                        float& cs1, float& sn1) {
  float sm = a + c0, df = a - c0;
  float adf = fabsf(df), tb = b + b, ab = fabsf(tb);
  float acmx, acmn;
  if (fabsf(a) > fabsf(c0)) { acmx = a; acmn = c0; } else { acmx = c0; acmn = a; }
  float rt;
  if (adf > ab)      { float t = ab / adf; rt = adf * __fsqrt_rn(1.f + t * t); }
  else if (adf < ab) { float t = adf / ab; rt = ab * __fsqrt_rn(1.f + t * t); }
  else               { rt = ab * __fsqrt_rn(2.f); }
  int sgn1;
  if (sm < 0.f)      { rt1 = 0.5f * (sm - rt); sgn1 = -1; rt2 = (acmx / rt1) * acmn - (b / rt1) * b; }
  else if (sm > 0.f) { rt1 = 0.5f * (sm + rt); sgn1 = 1;  rt2 = (acmx / rt1) * acmn - (b / rt1) * b; }
  else               { rt1 = 0.5f * rt; rt2 = -0.5f * rt; sgn1 = 1; }
  float cs; int sgn2;
  if (df >= 0.f) { cs = df + rt; sgn2 = 1; } else { cs = df - rt; sgn2 = -1; }
  float acs = fabsf(cs);
  if (acs > ab) {
    float ct = -tb / cs;
    sn1 = 1.f / __fsqrt_rn(1.f + ct * ct);
    cs1 = ct * sn1;
  } else {
    if (ab == 0.f) { cs1 = 1.f; sn1 = 0.f; }
    else { float tn = -cs / tb; cs1 = 1.f / __fsqrt_rn(1.f + tn * tn); sn1 = tn * cs1; }
  }
  if (sgn1 == sgn2) { float tn = cs1; cs1 = -sn1; sn1 = tn; }
}

#define D_(i) d[(i)-1]
#define E_(i) e[(i)-1]

__device__ void ssteqr3(float d[3], float e[2], float Z[3][3]) {
  const float eps    = 5.9604645e-08f;   // slamch('E') single
  const float eps2   = 3.5527137e-15f;
  const float safmin = 1.17549435e-38f;
  const float ssfmax = 3.0744573e+18f;   // sqrt(1/safmin)/3
  const float ssfmin = 3.0517578e-05f;   // sqrt(safmin)/eps^2
  const int n = 3;
  int jtot = 0, nmaxit = 90;
  int l1 = 1;

  while (true) {
    if (l1 > n) break;
    if (l1 > 1) E_(l1 - 1) = 0.f;
    int m = n;
    for (int mm = l1; mm <= n - 1; ++mm) {
      float tst = fabsf(E_(mm));
      if (tst == 0.f) { m = mm; break; }
      if (tst <= (__fsqrt_rn(fabsf(D_(mm))) * __fsqrt_rn(fabsf(D_(mm + 1)))) * eps) {
        E_(mm) = 0.f; m = mm; break;
      }
    }
    int l = l1, lsv = l, lend = m, lendsv = m;
    l1 = m + 1;
    if (lend == l) continue;

    float anorm = fabsf(D_(lend));
    for (int i2 = l; i2 <= lend - 1; ++i2) {
      anorm = fmaxf(anorm, fabsf(D_(i2)));
      anorm = fmaxf(anorm, fabsf(E_(i2)));
    }
    int iscale = 0;
    if (anorm == 0.f) continue;
    if (anorm > ssfmax) {
      iscale = 1; float mul = ssfmax / anorm;
      for (int i2 = l; i2 <= lend; ++i2) D_(i2) *= mul;
      for (int i2 = l; i2 <= lend - 1; ++i2) E_(i2) *= mul;
    } else if (anorm < ssfmin) {
      iscale = 2; float mul = ssfmin / anorm;
      for (int i2 = l; i2 <= lend; ++i2) D_(i2) *= mul;
      for (int i2 = l; i2 <= lend - 1; ++i2) E_(i2) *= mul;
    }

    if (fabsf(D_(lend)) < fabsf(D_(l))) { int t = l; l = lend; lend = t; }

    if (lend > l) {
      // ---- QL ----
      while (true) {
        int m2 = lend;
        if (l != lend) {
          for (int mm = l; mm <= lend - 1; ++mm) {
            float tst = fabsf(E_(mm)); tst = tst * tst;
            if (tst <= (eps2 * fabsf(D_(mm))) * fabsf(D_(mm + 1)) + safmin) { m2 = mm; break; }
          }
        }
        if (m2 < lend) E_(m2) = 0.f;
        float p = D_(l);
        if (m2 == l) { D_(l) = p; l = l + 1; if (l <= lend) continue; break; }
        if (m2 == l + 1) {
          float rt1, rt2, cc, ss;
          slaev2f(D_(l), E_(l), D_(l + 1), rt1, rt2, cc, ss);
          for (int i2 = 0; i2 < 3; ++i2) {
            float tmp = Z[i2][l];                 // col (l+1) 1-based
            Z[i2][l]     = cc * tmp - ss * Z[i2][l - 1];
            Z[i2][l - 1] = ss * tmp + cc * Z[i2][l - 1];
          }
          D_(l) = rt1; D_(l + 1) = rt2; E_(l) = 0.f;
          l = l + 2; if (l <= lend) continue; break;
        }
        if (jtot == nmaxit) break;
        ++jtot;
        float g = (D_(l + 1) - p) / (2.f * E_(l));
        float r = slapy2f(g, 1.f);
        float sgn_rg = (g >= 0.f) ? r : -r;
        g = D_(m2) - p + E_(l) / (g + sgn_rg);
        float s = 1.f, c = 1.f;
        p = 0.f;
        float csv[2], ssv[2];
        for (int i2 = m2 - 1; i2 >= l; --i2) {
          float f = s * E_(i2);
          float b = c * E_(i2);
          slartgf(g, f, c, s, r);
          if (i2 != m2 - 1) E_(i2 + 1) = r;
          g = D_(i2 + 1) - p;
          r = (D_(i2) - g) * s + 2.f * c * b;
          p = s * r;
          D_(i2 + 1) = g + p;
          g = c * r - b;
          csv[i2 - l] = c; ssv[i2 - l] = -s;
        }
        for (int j = m2 - 1; j >= l; --j) {
          float ct = csv[j - l], st = ssv[j - l];
          for (int i2 = 0; i2 < 3; ++i2) {
            float tmp = Z[i2][j];
            Z[i2][j]     = ct * tmp - st * Z[i2][j - 1];
            Z[i2][j - 1] = st * tmp + ct * Z[i2][j - 1];
          }
        }
        D_(l) = D_(l) - p;
        E_(l) = g;
      }
    } else {
      // ---- QR ----
      while (true) {
        int m2 = lend;
        if (l != lend) {
          for (int mm = l; mm >= lend + 1; --mm) {
            float tst = fabsf(E_(mm - 1)); tst = tst * tst;
            if (tst <= (eps2 * fabsf(D_(mm))) * fabsf(D_(mm - 1)) + safmin) { m2 = mm; break; }
          }
        }
        if (m2 > lend) E_(m2 - 1) = 0.f;
        float p = D_(l);
        if (m2 == l) { D_(l) = p; l = l - 1; if (l >= lend) continue; break; }
        if (m2 == l - 1) {
          float rt1, rt2, cc, ss;
          slaev2f(D_(l - 1), E_(l - 1), D_(l), rt1, rt2, cc, ss);
          for (int i2 = 0; i2 < 3; ++i2) {
            float tmp = Z[i2][l - 1];             // col l 1-based
            Z[i2][l - 1] = cc * tmp - ss * Z[i2][l - 2];
            Z[i2][l - 2] = ss * tmp + cc * Z[i2][l - 2];
          }
          D_(l - 1) = rt1; D_(l) = rt2; E_(l - 1) = 0.f;
          l = l - 2; if (l >= lend) continue; break;
        }
        if (jtot == nmaxit) break;
        ++jtot;
        float g = (D_(l - 1) - p) / (2.f * E_(l - 1));
        float r = slapy2f(g, 1.f);
        float sgn_rg = (g >= 0.f) ? r : -r;
        g = D_(m2) - p + E_(l - 1) / (g + sgn_rg);
        float s = 1.f, c = 1.f;
        p = 0.f;
        float csv[2], ssv[2];
        for (int i2 = m2; i2 <= l - 1; ++i2) {
          float f = s * E_(i2);
          float b = c * E_(i2);
          slartgf(g, f, c, s, r);
          if (i2 != m2) E_(i2 - 1) = r;
          g = D_(i2) - p;
          r = (D_(i2 + 1) - g) * s + 2.f * c * b;
          p = s * r;
          D_(i2) = g + p;
          g = c * r - b;
          csv[i2 - m2] = c; ssv[i2 - m2] = s;
        }
        for (int j = m2; j <= l - 1; ++j) {
          float ct = csv[j - m2], st = ssv[j - m2];
          for (int i2 = 0; i2 < 3; ++i2) {
            float tmp = Z[i2][j];
            Z[i2][j]     = ct * tmp - st * Z[i2][j - 1];
            Z[i2][j - 1] = st * tmp + ct * Z[i2][j - 1];
          }
        }
        D_(l) = D_(l) - p;
        E_(l - 1) = g;
      }
    }
    if (iscale == 1) {
      float mul = anorm / ssfmax;
      for (int i2 = lsv; i2 <= lendsv; ++i2) D_(i2) *= mul;
      for (int i2 = lsv; i2 <= lendsv - 1; ++i2) E_(i2) *= mul;
    } else if (iscale == 2) {
      float mul = anorm / ssfmin;
      for (int i2 = lsv; i2 <= lendsv; ++i2) D_(i2) *= mul;
      for (int i2 = lsv; i2 <= lendsv - 1; ++i2) E_(i2) *= mul;
    }
  }
  // selection sort ascending, swap eigenvector columns (as LAPACK)
  for (int ii = 2; ii <= n; ++ii) {
    int i2 = ii - 1, k = i2;
    float p = D_(i2);
    for (int j = ii; j <= n; ++j) if (D_(j) < p) { k = j; p = D_(j); }
    if (k != i2) {
      D_(k) = D_(i2); D_(i2) = p;
      for (int rr = 0; rr < 3; ++rr) {
        float t = Z[rr][i2 - 1]; Z[rr][i2 - 1] = Z[rr][k - 1]; Z[rr][k - 1] = t;
      }
    }
  }
}

// full ssyevd path for 3x3 (lower): ssytrd -> ssteqr -> sormtr; returns column 0
__device__ void eigh3_smallest(float a00, float a10, float a20, float a11, float a21, float a22,
                               float& nx, float& ny, float& nz) {
  float d[3], e[2];
  float Z[3][3] = {{1.f,0.f,0.f},{0.f,1.f,0.f},{0.f,0.f,1.f}};
  float tau, v2;
  {
    float alpha = a10, x = a20;
    float xnorm = fabsf(x);
    if (xnorm == 0.f) {
      tau = 0.f; v2 = 0.f;
      d[0] = a00; d[1] = a11; d[2] = a22;
      e[0] = alpha; e[1] = a21;
    } else {
      float beta = -copysignf(slapy2f(alpha, x), alpha);
      tau = (beta - alpha) / beta;
      v2 = x / (alpha - beta);
      // w = tau * A22 * v   (ssymv lower order)
      float w0 = (tau * a11) + tau * (a21 * v2);
      float w1 = (tau * a21) + (tau * v2) * a22;
      float ac = (-0.5f * tau) * (w0 + w1 * v2);
      w0 = w0 + ac;
      w1 = w1 + ac * v2;
      d[0] = a00;
      d[1] = (a11 - w0) - w0;            // dsyr2 order
      d[2] = (a22 - v2 * w1) - w1 * v2;
      e[0] = beta;
      e[1] = (a21 - v2 * w0) - w1;
    }
  }
  ssteqr3(d, e, Z);
  if (tau != 0.f) {   // sormtr: Z := H1 * Z
    for (int c = 0; c < 3; ++c) {
      float w = Z[1][c] + Z[2][c] * v2;
      float temp = (-tau) * w;
      Z[1][c] = Z[1][c] + temp;
      Z[2][c] = Z[2][c] + v2 * temp;
    }
  }
  nx = Z[0][0]; ny = Z[1][0]; nz = Z[2][0];
}

// ---------------- K0: init workspace ----------------
// slots layout: [set(2)][block(64)][4] u64: {key, xbits, ybits, zbits}, each tagged in low 10 bits
__global__ void k0_init(unsigned long long* slots, int* sample_idx) {
  int t = blockIdx.x * blockDim.x + threadIdx.x;
  if (t < 2 * FPS_BLOCKS * 4) slots[t] = 0ull;
  if (t == 0) sample_idx[0] = 0;
}

// ---------------- K1: farthest point sampling (persistent, 1023 steps) ----------------
// RELAXED-only cross-block exchange (no acquire/release -> no buffer_inv/wbl2 L2
// maintenance; sc1 accesses served at the coherence point). Each block publishes
// 4 self-tagged 64-bit words: its local best key and its candidate's xyz bits.
// Wave0 polls the 64 keys (lane i -> block i) and butterflies to the winner;
// waves 1..3 poll x/y/z payloads into LDS; winner's xyz is read from LDS —
// bit-exact relay, no remote pos[] load on the critical path.
__global__ __launch_bounds__(FPS_THREADS) void k1_fps(
    const float* __restrict__ pos,
    unsigned long long* __restrict__ slots,
    int* __restrict__ sample_idx) {
  __shared__ unsigned long long wbest[FPS_THREADS / 64];
  __shared__ float wxs[FPS_THREADS / 64], wys[FPS_THREADS / 64], wzs[FPS_THREADS / 64];
  __shared__ unsigned shx[FPS_BLOCKS], shy[FPS_BLOCKS], shz[FPS_BLOCKS];
  __shared__ int sh_wblk;
  const int tid = blockIdx.x * FPS_THREADS + threadIdx.x;
  float px[FPS_PPT], py[FPS_PPT], pz[FPS_PPT], md[FPS_PPT];
#pragma unroll
  for (int k = 0; k < FPS_PPT; ++k) {
    int p = tid + k * (FPS_BLOCKS * FPS_THREADS);
    px[k] = pos[3 * p]; py[k] = pos[3 * p + 1]; pz[k] = pos[3 * p + 2];
    md[k] = 1e10f;
  }
  float lx = pos[0], ly = pos[1], lz = pos[2];
  for (int s = 0; s < NUM_SAMPLE - 1; ++s) {
    unsigned long long best = 0ull;
    int bk = 0;
#pragma unroll
    for (int k = 0; k < FPS_PPT; ++k) {
      float dx = subrn(px[k], lx), dy = subrn(py[k], ly), dz = subrn(pz[k], lz);
      float d2 = addrn(addrn(mulrn(dx, dx), mulrn(dy, dy)), mulrn(dz, dz));
      float m = fminf(md[k], d2);
      md[k] = m;
      // key: [63:32]=f32 bits (nonneg), [31:10]=0x3FFFFF-idx (smaller idx wins), [9:0]=tag
      unsigned long long key =
          ((unsigned long long)__float_as_uint(m) << 32) |
          ((unsigned)(0x3FFFFF - (tid + k * (FPS_BLOCKS * FPS_THREADS))) << 10);
      if (key > best) { best = key; bk = k; }
    }
    float bx = px[bk], by = py[bk], bz = pz[bk];
#pragma unroll
    for (int off = 32; off > 0; off >>= 1) {
      unsigned long long ok = (unsigned long long)__shfl_down((long long)best, (unsigned)off, 64);
      float ox = __shfl_down(bx, (unsigned)off, 64);
      float oy = __shfl_down(by, (unsigned)off, 64);
      float oz = __shfl_down(bz, (unsigned)off, 64);
      if (ok > best) { best = ok; bx = ox; by = oy; bz = oz; }
    }
    const int lane = threadIdx.x & 63, wv = threadIdx.x >> 6;
    if (lane == 0) { wbest[wv] = best; wxs[wv] = bx; wys[wv] = by; wzs[wv] = bz; }
    __syncthreads();
    const unsigned want = (unsigned)(s + 1);   // 10-bit tag, 1..1023, never 0
    unsigned long long* base = slots + (size_t)(s & 1) * (FPS_BLOCKS * 4);
    if (threadIdx.x == 0) {
      unsigned long long b = wbest[0];
      float X = wxs[0], Y = wys[0], Zv = wzs[0];
#pragma unroll
      for (int w = 1; w < FPS_THREADS / 64; ++w)
        if (wbest[w] > b) { b = wbest[w]; X = wxs[w]; Y = wys[w]; Zv = wzs[w]; }
      unsigned long long* my = base + blockIdx.x * 4;
      __hip_atomic_store(my + 0, b | want, __ATOMIC_RELAXED, __HIP_MEMORY_SCOPE_AGENT);
      __hip_atomic_store(my + 1, ((unsigned long long)__float_as_uint(X) << 32) | want,
                         __ATOMIC_RELAXED, __HIP_MEMORY_SCOPE_AGENT);
      __hip_atomic_store(my + 2, ((unsigned long long)__float_as_uint(Y) << 32) | want,
                         __ATOMIC_RELAXED, __HIP_MEMORY_SCOPE_AGENT);
      __hip_atomic_store(my + 3, ((unsigned long long)__float_as_uint(Zv) << 32) | want,
                         __ATOMIC_RELAXED, __HIP_MEMORY_SCOPE_AGENT);
    }
    // all 256 threads poll: group g (=wave) polls word g of block i's 4-word slot
    {
      const int grp = threadIdx.x >> 6;
      const int i = threadIdx.x & 63;
      unsigned long long v;
      do {
        v = __hip_atomic_load(base + i * 4 + grp, __ATOMIC_RELAXED, __HIP_MEMORY_SCOPE_AGENT);
      } while ((unsigned)(v & 1023ull) != want);
      if (grp == 0) {
#pragma unroll
        for (int mk = 1; mk < 64; mk <<= 1) {
          unsigned long long o = (unsigned long long)__shfl_xor((long long)v, mk, 64);
          if (o > v) v = o;
        }
        if (i == 0) {
          int widx = 0x3FFFFF - (int)((v >> 10) & 0x3FFFFFull);
          sh_wblk = (widx & (FPS_BLOCKS * FPS_THREADS - 1)) >> 8;  // owning block
          if (blockIdx.x == 0) sample_idx[s + 1] = widx;
        }
      } else if (grp == 1) { shx[i] = (unsigned)(v >> 32); }
      else if (grp == 2) { shy[i] = (unsigned)(v >> 32); }
      else               { shz[i] = (unsigned)(v >> 32); }
    }
    __syncthreads();
    const int wb = sh_wblk;
    lx = __uint_as_float(shx[wb]);
    ly = __uint_as_float(shy[wb]);
    lz = __uint_as_float(shz[wb]);
  }
}

// ---------------- K2: gather samples, KNN normals, MLP, softmax/argmax ----------------
__global__ __launch_bounds__(64) void k2_samples(
    const float* __restrict__ pos, const float* __restrict__ col,
    const float* __restrict__ W1, const float* __restrict__ b1,
    const float* __restrict__ W2, const float* __restrict__ b2,
    const float* __restrict__ W3, const float* __restrict__ b3,
    const int* __restrict__ sample_idx,
    float4* __restrict__ sp4g, float* __restrict__ featd, int* __restrict__ lbl) {
  __shared__ float4 sp[NUM_SAMPLE];
  __shared__ float hbuf[64][129];
  const int tid = threadIdx.x;
  for (int i = tid; i < NUM_SAMPLE; i += 64) {
    int idx = sample_idx[i];
    float x = pos[3 * idx], y = pos[3 * idx + 1], z = pos[3 * idx + 2];
    float nrm = addrn(addrn(mulrn(x, x), mulrn(y, y)), mulrn(z, z));
    float4 v = make_float4(x, y, z, nrm);
    sp[i] = v;
    if (blockIdx.x == 0) sp4g[i] = v;
  }
  __syncthreads();
  const int r = blockIdx.x * 64 + tid;

  // ---- top-17 nearest (stable ascending (d2, idx)) ----
  float bd[17]; int bi[17];
#pragma unroll
  for (int t = 0; t < 17; ++t) { bd[t] = 3.402823466e+38f; bi[t] = -1; }
  float4 pr = sp[r];
  for (int j = 0; j < NUM_SAMPLE; ++j) {
    float4 q = sp[j];
    float dot = fmaf(pr.z, q.z, fmaf(pr.y, q.y, mulrn(pr.x, q.x)));
    float d2 = subrn(addrn(pr.w, q.w), mulrn(2.f, dot));
    if (d2 < bd[16]) {
#pragma unroll
      for (int p = 16; p >= 1; --p) {
        bool a = d2 < bd[p - 1];
        bool bsel = d2 < bd[p];
        float nv = a ? bd[p - 1] : (bsel ? d2 : bd[p]);
        int niv = a ? bi[p - 1] : (bsel ? j : bi[p]);
        bd[p] = nv; bi[p] = niv;
      }
      if (d2 < bd[0]) { bd[0] = d2; bi[0] = j; }
    }
  }

  // ---- mean / covariance over neighbors 1..16 (sorted order) ----
  float mx = 0.f, my = 0.f, mz = 0.f;
#pragma unroll
  for (int k = 1; k <= 16; ++k) {
    float4 q = sp[bi[k]];
    mx = addrn(mx, q.x); my = addrn(my, q.y); mz = addrn(mz, q.z);
  }
  mx = mulrn(mx, 0.0625f); my = mulrn(my, 0.0625f); mz = mulrn(mz, 0.0625f);
  float c00 = 0.f, c01 = 0.f, c02 = 0.f, c11 = 0.f, c12 = 0.f, c22 = 0.f;
#pragma unroll
  for (int k = 1; k <= 16; ++k) {
    float4 q = sp[bi[k]];
    float dx = subrn(q.x, mx), dy = subrn(q.y, my), dz = subrn(q.z, mz);
    c00 = addrn(c00, mulrn(dx, dx)); c01 = addrn(c01, mulrn(dx, dy));
    c02 = addrn(c02, mulrn(dx, dz)); c11 = addrn(c11, mulrn(dy, dy));
    c12 = addrn(c12, mulrn(dy, dz)); c22 = addrn(c22, mulrn(dz, dz));
  }
  c00 /= 15.f; c01 /= 15.f; c02 /= 15.f; c11 /= 15.f; c12 /= 15.f; c22 /= 15.f;

  float n0, n1, n2;
  eigh3_smallest(c00, c01, c02, c11, c12, c22, n0, n1, n2);
  float nn = __fsqrt_rn(addrn(addrn(mulrn(n0, n0), mulrn(n1, n1)), mulrn(n2, n2)));
  float den = addrn(nn, 1e-8f);
  n0 /= den; n1 /= den; n2 /= den;

  // ---- MLP ----
  int myidx = sample_idx[r];
  float f9[9] = { pr.x, pr.y, pr.z,
                  col[3 * myidx], col[3 * myidx + 1], col[3 * myidx + 2],
                  n0, n1, n2 };
  for (int jo = 0; jo < 128; ++jo) {
    float acc = 0.f;
#pragma unroll
    for (int k = 0; k < 9; ++k) acc = fmaf(f9[k], W1[k * 128 + jo], acc);
    acc += b1[jo];
    hbuf[tid][jo] = fmaxf(acc, 0.f);
  }
  float pd[13];
#pragma unroll
  for (int c = 0; c < 13; ++c) pd[c] = 0.f;
  for (int io = 0; io < 128; io += 16) {
    float acc[16];
#pragma unroll
    for (int t = 0; t < 16; ++t) acc[t] = 0.f;
    for (int j = 0; j < 128; ++j) {
      float hj = hbuf[tid][j];
#pragma unroll
      for (int t = 0; t < 16; ++t) acc[t] = fmaf(hj, W2[j * 128 + io + t], acc[t]);
    }
#pragma unroll
    for (int t = 0; t < 16; ++t) {
      float h2 = fmaxf(acc[t] + b2[io + t], 0.f);
#pragma unroll
      for (int c = 0; c < 13; ++c) pd[c] = fmaf(h2, W3[(io + t) * 13 + c], pd[c]);
    }
  }
#pragma unroll
  for (int c = 0; c < 13; ++c) pd[c] += b3[c];
  float mmax = pd[0];
#pragma unroll
  for (int c = 1; c < 13; ++c) mmax = fmaxf(mmax, pd[c]);
  float es = 0.f, ev[13];
#pragma unroll
  for (int c = 0; c < 13; ++c) { ev[c] = expf(pd[c] - mmax); es += ev[c]; }
#pragma unroll
  for (int c = 0; c < 13; ++c) featd[r * 13 + c] = ev[c] / es;
  int am = 0; float bv = pd[0];
#pragma unroll
  for (int c = 1; c < 13; ++c) { if (pd[c] > bv) { bv = pd[c]; am = c; } }
  lbl[r] = am;
}

// ---------------- K3: nearest sample + gather outputs ----------------
__global__ __launch_bounds__(256) void k3_assign(
    const float* __restrict__ pos,
    const float4* __restrict__ sp4g,
    const float* __restrict__ featd,
    const int* __restrict__ lbl,
    float* __restrict__ out) {
  __shared__ float4 sp[NUM_SAMPLE];
  for (int i = threadIdx.x; i < NUM_SAMPLE; i += 256) sp[i] = sp4g[i];
  __syncthreads();
  int i = blockIdx.x * 256 + threadIdx.x;
  float x = pos[3 * i], y = pos[3 * i + 1], z = pos[3 * i + 2];
  float an = addrn(addrn(mulrn(x, x), mulrn(y, y)), mulrn(z, z));
  float bestd = 3.402823466e+38f; int bestj = 0;
#pragma unroll 4
  for (int j = 0; j < NUM_SAMPLE; ++j) {
    float4 q = sp[j];
    float dot = fmaf(z, q.z, fmaf(y, q.y, mulrn(x, q.x)));
    float d2 = subrn(addrn(an, q.w), mulrn(2.f, dot));
    if (d2 < bestd) { bestd = d2; bestj = j; }
  }
  const float* fr = featd + bestj * 13;
  float* o = out + (size_t)i * 13;
#pragma unroll
  for (int c = 0; c < 13; ++c) o[c] = fr[c];
  out[(size_t)N_TOTAL * 13 + i] = (float)lbl[bestj];
}

extern "C" void kernel_launch(void* const* d_in, const int* in_sizes, int n_in,
                              void* d_out, int out_size, void* d_ws, size_t ws_size,
                              hipStream_t stream) {
  (void)in_sizes; (void)n_in; (void)out_size; (void)ws_size;
  const float* pos = (const float*)d_in[0];
  const float* col = (const float*)d_in[1];
  const float* W1 = (const float*)d_in[2];
  const float* b1 = (const float*)d_in[3];
  const float* W2 = (const float*)d_in[4];
  const float* b2 = (const float*)d_in[5];
  const float* W3 = (const float*)d_in[6];
  const float* b3 = (const float*)d_in[7];
  float* out = (float*)d_out;

  char* w = (char*)d_ws;
  unsigned long long* slots = (unsigned long long*)(w);          //  4 KiB (2 sets x 64 x 4)
  int* sample_idx = (int*)(w + 8192);                            //  4 KiB
  float4* sp4g = (float4*)(w + 16384);                           // 16 KiB
  float* featd = (float*)(w + 32768);                            // 52 KiB
  int* lbl = (int*)(w + 32768 + 53248);                          //  4 KiB

  k0_init<<<2, 256, 0, stream>>>(slots, sample_idx);
  k1_fps<<<FPS_BLOCKS, FPS_THREADS, 0, stream>>>(pos, slots, sample_idx);
  k2_samples<<<16, 64, 0, stream>>>(pos, col, W1, b1, W2, b2, W3, b3,
                                    sample_idx, sp4g, featd, lbl);
  k3_assign<<<N_TOTAL / 256, 256, 0, stream>>>(pos, sp4g, featd, lbl, out);
}

// Round 4
// 2702.685 us; speedup vs baseline: 1.8903x; 1.8254x over previous
//
#include <hip/hip_runtime.h>
#include <math.h>

#define N_TOTAL    262144
#define NUM_SAMPLE 1024
#define FPS_BLOCKS 64
#define FPS_THREADS 256
#define FPS_PPT (N_TOTAL / (FPS_BLOCKS * FPS_THREADS))   // 16
#define M_CAND 16
#define POOL (FPS_BLOCKS * M_CAND)                        // 1024
#define SEL_CAP 1023

__device__ __forceinline__ float addrn(float a, float b) { return __fadd_rn(a, b); }
__device__ __forceinline__ float subrn(float a, float b) { return __fsub_rn(a, b); }
__device__ __forceinline__ float mulrn(float a, float b) { return __fmul_rn(a, b); }

__device__ __forceinline__ float d2rn(float ax, float ay, float az,
                                      float bx, float by, float bz) {
  float dx = subrn(ax, bx), dy = subrn(ay, by), dz = subrn(az, bz);
  return addrn(addrn(mulrn(dx, dx), mulrn(dy, dy)), mulrn(dz, dz));
}

// ---------------- LAPACK emulation (f32) ----------------
__device__ __forceinline__ float slapy2f(float x, float y) {
  float xa = fabsf(x), ya = fabsf(y);
  float w = fmaxf(xa, ya), z = fminf(xa, ya);
  if (z == 0.f) return w;
  float t = z / w;
  return w * __fsqrt_rn(1.f + t * t);
}

__device__ __forceinline__ void slartgf(float f, float g, float& c, float& s, float& r) {
  if (g == 0.f) { c = 1.f; s = 0.f; r = f; }
  else if (f == 0.f) { c = 0.f; s = (g > 0.f) ? 1.f : -1.f; r = fabsf(g); }
  else {
    float d = __fsqrt_rn(f * f + g * g);
    c = fabsf(f) / d;
    r = (f >= 0.f) ? d : -d;
    s = g / r;
  }
}

__device__ void slaev2f(float a, float b, float c0, float& rt1, float& rt2,
                        float& cs1, float& sn1) {
  float sm = a + c0, df = a - c0;
  float adf = fabsf(df), tb = b + b, ab = fabsf(tb);
  float acmx, acmn;
  if (fabsf(a) > fabsf(c0)) { acmx = a; acmn = c0; } else { acmx = c0; acmn = a; }
  float rt;
  if (adf > ab)      { float t = ab / adf; rt = adf * __fsqrt_rn(1.f + t * t); }
  else if (adf < ab) { float t = adf / ab; rt = ab * __fsqrt_rn(1.f + t * t); }
  else               { rt = ab * __fsqrt_rn(2.f); }
  int sgn1;
  if (sm < 0.f)      { rt1 = 0.5f * (sm - rt); sgn1 = -1; rt2 = (acmx / rt1) * acmn - (b / rt1) * b; }
  else if (sm > 0.f) { rt1 = 0.5f * (sm + rt); sgn1 = 1;  rt2 = (acmx / rt1) * acmn - (b / rt1) * b; }
  else               { rt1 = 0.5f * rt; rt2 = -0.5f * rt; sgn1 = 1; }
  float cs; int sgn2;
  if (df >= 0.f) { cs = df + rt; sgn2 = 1; } else { cs = df - rt; sgn2 = -1; }
  float acs = fabsf(cs);
  if (acs > ab) {
    float ct = -tb / cs;
    sn1 = 1.f / __fsqrt_rn(1.f + ct * ct);
    cs1 = ct * sn1;
  } else {
    if (ab == 0.f) { cs1 = 1.f; sn1 = 0.f; }
    else { float tn = -cs / tb; cs1 = 1.f / __fsqrt_rn(1.f + tn * tn); sn1 = tn * cs1; }
  }
  if (sgn1 == sgn2) { float tn = cs1; cs1 = -sn1; sn1 = tn; }
}

#define D_(i) d[(i)-1]
#define E_(i) e[(i)-1]

__device__ void ssteqr3(float d[3], float e[2], float Z[3][3]) {
  const float eps    = 5.9604645e-08f;
  const float eps2   = 3.5527137e-15f;
  const float safmin = 1.17549435e-38f;
  const float ssfmax = 3.0744573e+18f;
  const float ssfmin = 3.0517578e-05f;
  const int n = 3;
  int jtot = 0, nmaxit = 90;
  int l1 = 1;

  while (true) {
    if (l1 > n) break;
    if (l1 > 1) E_(l1 - 1) = 0.f;
    int m = n;
    for (int mm = l1; mm <= n - 1; ++mm) {
      float tst = fabsf(E_(mm));
      if (tst == 0.f) { m = mm; break; }
      if (tst <= (__fsqrt_rn(fabsf(D_(mm))) * __fsqrt_rn(fabsf(D_(mm + 1)))) * eps) {
        E_(mm) = 0.f; m = mm; break;
      }
    }
    int l = l1, lsv = l, lend = m, lendsv = m;
    l1 = m + 1;
    if (lend == l) continue;

    float anorm = fabsf(D_(lend));
    for (int i2 = l; i2 <= lend - 1; ++i2) {
      anorm = fmaxf(anorm, fabsf(D_(i2)));
      anorm = fmaxf(anorm, fabsf(E_(i2)));
    }
    int iscale = 0;
    if (anorm == 0.f) continue;
    if (anorm > ssfmax) {
      iscale = 1; float mul = ssfmax / anorm;
      for (int i2 = l; i2 <= lend; ++i2) D_(i2) *= mul;
      for (int i2 = l; i2 <= lend - 1; ++i2) E_(i2) *= mul;
    } else if (anorm < ssfmin) {
      iscale = 2; float mul = ssfmin / anorm;
      for (int i2 = l; i2 <= lend; ++i2) D_(i2) *= mul;
      for (int i2 = l; i2 <= lend - 1; ++i2) E_(i2) *= mul;
    }

    if (fabsf(D_(lend)) < fabsf(D_(l))) { int t = l; l = lend; lend = t; }

    if (lend > l) {
      while (true) {
        int m2 = lend;
        if (l != lend) {
          for (int mm = l; mm <= lend - 1; ++mm) {
            float tst = fabsf(E_(mm)); tst = tst * tst;
            if (tst <= (eps2 * fabsf(D_(mm))) * fabsf(D_(mm + 1)) + safmin) { m2 = mm; break; }
          }
        }
        if (m2 < lend) E_(m2) = 0.f;
        float p = D_(l);
        if (m2 == l) { D_(l) = p; l = l + 1; if (l <= lend) continue; break; }
        if (m2 == l + 1) {
          float rt1, rt2, cc, ss;
          slaev2f(D_(l), E_(l), D_(l + 1), rt1, rt2, cc, ss);
          for (int i2 = 0; i2 < 3; ++i2) {
            float tmp = Z[i2][l];
            Z[i2][l]     = cc * tmp - ss * Z[i2][l - 1];
            Z[i2][l - 1] = ss * tmp + cc * Z[i2][l - 1];
          }
          D_(l) = rt1; D_(l + 1) = rt2; E_(l) = 0.f;
          l = l + 2; if (l <= lend) continue; break;
        }
        if (jtot == nmaxit) break;
        ++jtot;
        float g = (D_(l + 1) - p) / (2.f * E_(l));
        float r = slapy2f(g, 1.f);
        float sgn_rg = (g >= 0.f) ? r : -r;
        g = D_(m2) - p + E_(l) / (g + sgn_rg);
        float s = 1.f, c = 1.f;
        p = 0.f;
        float csv[2], ssv[2];
        for (int i2 = m2 - 1; i2 >= l; --i2) {
          float f = s * E_(i2);
          float b = c * E_(i2);
          slartgf(g, f, c, s, r);
          if (i2 != m2 - 1) E_(i2 + 1) = r;
          g = D_(i2 + 1) - p;
          r = (D_(i2) - g) * s + 2.f * c * b;
          p = s * r;
          D_(i2 + 1) = g + p;
          g = c * r - b;
          csv[i2 - l] = c; ssv[i2 - l] = -s;
        }
        for (int j = m2 - 1; j >= l; --j) {
          float ct = csv[j - l], st = ssv[j - l];
          for (int i2 = 0; i2 < 3; ++i2) {
            float tmp = Z[i2][j];
            Z[i2][j]     = ct * tmp - st * Z[i2][j - 1];
            Z[i2][j - 1] = st * tmp + ct * Z[i2][j - 1];
          }
        }
        D_(l) = D_(l) - p;
        E_(l) = g;
      }
    } else {
      while (true) {
        int m2 = lend;
        if (l != lend) {
          for (int mm = l; mm >= lend + 1; --mm) {
            float tst = fabsf(E_(mm - 1)); tst = tst * tst;
            if (tst <= (eps2 * fabsf(D_(mm))) * fabsf(D_(mm - 1)) + safmin) { m2 = mm; break; }
          }
        }
        if (m2 > lend) E_(m2 - 1) = 0.f;
        float p = D_(l);
        if (m2 == l) { D_(l) = p; l = l - 1; if (l >= lend) continue; break; }
        if (m2 == l - 1) {
          float rt1, rt2, cc, ss;
          slaev2f(D_(l - 1), E_(l - 1), D_(l), rt1, rt2, cc, ss);
          for (int i2 = 0; i2 < 3; ++i2) {
            float tmp = Z[i2][l - 1];
            Z[i2][l - 1] = cc * tmp - ss * Z[i2][l - 2];
            Z[i2][l - 2] = ss * tmp + cc * Z[i2][l - 2];
          }
          D_(l - 1) = rt1; D_(l) = rt2; E_(l - 1) = 0.f;
          l = l - 2; if (l >= lend) continue; break;
        }
        if (jtot == nmaxit) break;
        ++jtot;
        float g = (D_(l - 1) - p) / (2.f * E_(l - 1));
        float r = slapy2f(g, 1.f);
        float sgn_rg = (g >= 0.f) ? r : -r;
        g = D_(m2) - p + E_(l - 1) / (g + sgn_rg);
        float s = 1.f, c = 1.f;
        p = 0.f;
        float csv[2], ssv[2];
        for (int i2 = m2; i2 <= l - 1; ++i2) {
          float f = s * E_(i2);
          float b = c * E_(i2);
          slartgf(g, f, c, s, r);
          if (i2 != m2) E_(i2 - 1) = r;
          g = D_(i2) - p;
          r = (D_(i2 + 1) - g) * s + 2.f * c * b;
          p = s * r;
          D_(i2) = g + p;
          g = c * r - b;
          csv[i2 - m2] = c; ssv[i2 - m2] = s;
        }
        for (int j = m2; j <= l - 1; ++j) {
          float ct = csv[j - m2], st = ssv[j - m2];
          for (int i2 = 0; i2 < 3; ++i2) {
            float tmp = Z[i2][j];
            Z[i2][j]     = ct * tmp - st * Z[i2][j - 1];
            Z[i2][j - 1] = st * tmp + ct * Z[i2][j - 1];
          }
        }
        D_(l) = D_(l) - p;
        E_(l - 1) = g;
      }
    }
    if (iscale == 1) {
      float mul = anorm / ssfmax;
      for (int i2 = lsv; i2 <= lendsv; ++i2) D_(i2) *= mul;
      for (int i2 = lsv; i2 <= lendsv - 1; ++i2) E_(i2) *= mul;
    } else if (iscale == 2) {
      float mul = anorm / ssfmin;
      for (int i2 = lsv; i2 <= lendsv; ++i2) D_(i2) *= mul;
      for (int i2 = lsv; i2 <= lendsv - 1; ++i2) E_(i2) *= mul;
    }
  }
  for (int ii = 2; ii <= n; ++ii) {
    int i2 = ii - 1, k = i2;
    float p = D_(i2);
    for (int j = ii; j <= n; ++j) if (D_(j) < p) { k = j; p = D_(j); }
    if (k != i2) {
      D_(k) = D_(i2); D_(i2) = p;
      for (int rr = 0; rr < 3; ++rr) {
        float t = Z[rr][i2 - 1]; Z[rr][i2 - 1] = Z[rr][k - 1]; Z[rr][k - 1] = t;
      }
    }
  }
}

__device__ void eigh3_smallest(float a00, float a10, float a20, float a11, float a21, float a22,
                               float& nx, float& ny, float& nz) {
  float d[3], e[2];
  float Z[3][3] = {{1.f,0.f,0.f},{0.f,1.f,0.f},{0.f,0.f,1.f}};
  float tau, v2;
  {
    float alpha = a10, x = a20;
    float xnorm = fabsf(x);
    if (xnorm == 0.f) {
      tau = 0.f; v2 = 0.f;
      d[0] = a00; d[1] = a11; d[2] = a22;
      e[0] = alpha; e[1] = a21;
    } else {
      float beta = -copysignf(slapy2f(alpha, x), alpha);
      tau = (beta - alpha) / beta;
      v2 = x / (alpha - beta);
      float w0 = (tau * a11) + tau * (a21 * v2);
      float w1 = (tau * a21) + (tau * v2) * a22;
      float ac = (-0.5f * tau) * (w0 + w1 * v2);
      w0 = w0 + ac;
      w1 = w1 + ac * v2;
      d[0] = a00;
      d[1] = (a11 - w0) - w0;
      d[2] = (a22 - v2 * w1) - w1 * v2;
      e[0] = beta;
      e[1] = (a21 - v2 * w0) - w1;
    }
  }
  ssteqr3(d, e, Z);
  if (tau != 0.f) {
    for (int c = 0; c < 3; ++c) {
      float w = Z[1][c] + Z[2][c] * v2;
      float temp = (-tau) * w;
      Z[1][c] = Z[1][c] + temp;
      Z[2][c] = Z[2][c] + v2 * temp;
    }
  }
  nx = Z[0][0]; ny = Z[1][0]; nz = Z[2][0];
}

// ---------------- K0: init workspace ----------------
__global__ void k0_init(unsigned long long* cand, int* sample_idx) {
  int t = blockIdx.x * blockDim.x + threadIdx.x;
  if (t < 2 * FPS_BLOCKS * M_CAND * 4) cand[t] = 0ull;
  if (t == 0) sample_idx[0] = 0;
}

// ---------------- K1: batched farthest point sampling ----------------
// Per batch: each block publishes its top-16 candidates (key + bit-exact xyz,
// relaxed tagged words). Every block mirrors the 1024-entry pool in LDS and
// picks locally while best_key >= T (T = max_b of b's 16th key): unpublished
// points are strictly < their block's 16th and keys only decrease, so the
// pool provably contains the global argmax -> picks are bit-exact. First
// pick per batch is always valid -> guaranteed progress.
__global__ __launch_bounds__(FPS_THREADS) void k1_fps(
    const float* __restrict__ pos,
    unsigned long long* __restrict__ cand,
    int* __restrict__ sample_idx) {
  __shared__ unsigned long long pool_key[POOL];
  __shared__ float pool_x[POOL], pool_y[POOL], pool_z[POOL];
  __shared__ float sel_x[SEL_CAP], sel_y[SEL_CAP], sel_z[SEL_CAP];
  __shared__ unsigned long long btop_key[M_CAND];
  __shared__ float btop_x[M_CAND], btop_y[M_CAND], btop_z[M_CAND];
  __shared__ unsigned long long red_k[4];
  __shared__ float red_x[4], red_y[4], red_z[4];
  __shared__ unsigned long long sh_bkey;
  __shared__ float sh_px, sh_py, sh_pz;
  __shared__ int sh_stop;

  const int tidx = threadIdx.x;
  const int lane = tidx & 63, wv = tidx >> 6;
  const int gtid = blockIdx.x * FPS_THREADS + tidx;

  float px[FPS_PPT], py[FPS_PPT], pz[FPS_PPT], md[FPS_PPT];
#pragma unroll
  for (int k = 0; k < FPS_PPT; ++k) {
    int p = gtid + k * (FPS_BLOCKS * FPS_THREADS);
    px[k] = pos[3 * p]; py[k] = pos[3 * p + 1]; pz[k] = pos[3 * p + 2];
    md[k] = 1e10f;
  }
  if (tidx == 0) { sel_x[0] = pos[0]; sel_y[0] = pos[1]; sel_z[0] = pos[2]; }
  __syncthreads();
  int sel_cnt = 1;
  int total = 0;
  int bt = 0;
  while (total < NUM_SAMPLE - 1) {
    ++bt;
    // ---- Phase A: owner md updates vs previous batch's picks ----
    for (int s = 0; s < sel_cnt; ++s) {
      float lx = sel_x[s], ly = sel_y[s], lz = sel_z[s];
#pragma unroll
      for (int k = 0; k < FPS_PPT; ++k)
        md[k] = fminf(md[k], d2rn(px[k], py[k], pz[k], lx, ly, lz));
    }
    __syncthreads();
    // ---- block top-16 (16 rounds of argmax+exclude) ----
    {
      float wmd[FPS_PPT];
#pragma unroll
      for (int k = 0; k < FPS_PPT; ++k) wmd[k] = md[k];
      for (int r = 0; r < M_CAND; ++r) {
        unsigned long long best = 0ull; int bk = 0;
#pragma unroll
        for (int k = 0; k < FPS_PPT; ++k) {
          if (wmd[k] >= 0.f) {
            unsigned long long key =
                ((unsigned long long)__float_as_uint(wmd[k]) << 32) |
                ((unsigned)(0x3FFFFF - (gtid + k * (FPS_BLOCKS * FPS_THREADS))) << 10);
            if (key > best) { best = key; bk = k; }
          }
        }
        float bx = px[bk], by = py[bk], bz = pz[bk];
#pragma unroll
        for (int off = 32; off > 0; off >>= 1) {
          unsigned long long ok = (unsigned long long)__shfl_down((long long)best, (unsigned)off, 64);
          float ox = __shfl_down(bx, (unsigned)off, 64);
          float oy = __shfl_down(by, (unsigned)off, 64);
          float oz = __shfl_down(bz, (unsigned)off, 64);
          if (ok > best) { best = ok; bx = ox; by = oy; bz = oz; }
        }
        if (lane == 0) { red_k[wv] = best; red_x[wv] = bx; red_y[wv] = by; red_z[wv] = bz; }
        __syncthreads();
        if (tidx == 0) {
          unsigned long long b = red_k[0]; float X = red_x[0], Y = red_y[0], Zz = red_z[0];
#pragma unroll
          for (int w = 1; w < 4; ++w)
            if (red_k[w] > b) { b = red_k[w]; X = red_x[w]; Y = red_y[w]; Zz = red_z[w]; }
          btop_key[r] = b; btop_x[r] = X; btop_y[r] = Y; btop_z[r] = Zz;
          sh_bkey = b;
        }
        __syncthreads();
        unsigned long long wb = sh_bkey;
#pragma unroll
        for (int k = 0; k < FPS_PPT; ++k) {
          if (wmd[k] >= 0.f) {
            unsigned long long key =
                ((unsigned long long)__float_as_uint(wmd[k]) << 32) |
                ((unsigned)(0x3FFFFF - (gtid + k * (FPS_BLOCKS * FPS_THREADS))) << 10);
            if (key == wb) wmd[k] = -1.f;
          }
        }
        __syncthreads();
      }
    }
    // ---- publish (wave 0: one word per lane) ----
    const unsigned tag = (unsigned)bt & 1023u;
    unsigned long long* setbase = cand + (size_t)(bt & 1) * (FPS_BLOCKS * M_CAND * 4);
    if (wv == 0) {
      int c = lane >> 2, part = lane & 3;
      unsigned long long v;
      if (part == 0)      v = btop_key[c] | tag;   // key low 10 bits are 0
      else if (part == 1) v = ((unsigned long long)__float_as_uint(btop_x[c]) << 32) | tag;
      else if (part == 2) v = ((unsigned long long)__float_as_uint(btop_y[c]) << 32) | tag;
      else                v = ((unsigned long long)__float_as_uint(btop_z[c]) << 32) | tag;
      __hip_atomic_store(setbase + blockIdx.x * (M_CAND * 4) + lane, v,
                         __ATOMIC_RELAXED, __HIP_MEMORY_SCOPE_AGENT);
    }
    // ---- Phase B: poll all 4096 words (thread i -> words [16i,16i+16)) ----
    {
      const int base_w = tidx * 16;
      unsigned done = 0;
      while (done != 0xFFFFu) {
        for (int j = 0; j < 16; ++j) {
          if (!((done >> j) & 1u)) {
            unsigned long long v = __hip_atomic_load(setbase + base_w + j,
                                                     __ATOMIC_RELAXED, __HIP_MEMORY_SCOPE_AGENT);
            if ((unsigned)(v & 1023ull) == tag) {
              done |= 1u << j;
              int w = base_w + j;
              int e = ((w >> 6) << 4) | ((w >> 2) & 15);
              int part = w & 3;
              if (part == 0)      pool_key[e] = v & 0xFFFFFFFFFFFFFC00ull;
              else if (part == 1) pool_x[e] = __uint_as_float((unsigned)(v >> 32));
              else if (part == 2) pool_y[e] = __uint_as_float((unsigned)(v >> 32));
              else                pool_z[e] = __uint_as_float((unsigned)(v >> 32));
            }
          }
        }
      }
    }
    __syncthreads();
    // ---- T bound ----
    if (tidx == 0) {
      unsigned long long T = 0;
      for (int b = 0; b < FPS_BLOCKS; ++b) {
        unsigned long long v = pool_key[b * M_CAND + (M_CAND - 1)];
        if (v > T) T = v;
      }
      red_k[0] = T;
    }
    __syncthreads();
    const unsigned long long Tkey = red_k[0];
    // ---- Phase C: local batch selection (identical in every block) ----
    int picks = 0;
    for (;;) {
      unsigned long long best = 0ull;
#pragma unroll
      for (int j = 0; j < 4; ++j) {
        unsigned long long v = pool_key[tidx * 4 + j];
        if (v > best) best = v;
      }
#pragma unroll
      for (int off = 32; off > 0; off >>= 1) {
        unsigned long long o = (unsigned long long)__shfl_down((long long)best, (unsigned)off, 64);
        if (o > best) best = o;
      }
      if (lane == 0) red_k[wv] = best;
      __syncthreads();
      if (tidx == 0) {
        unsigned long long b = red_k[0];
#pragma unroll
        for (int w = 1; w < 4; ++w) if (red_k[w] > b) b = red_k[w];
        sh_bkey = b;
        sh_stop = (b < Tkey) || (total + picks >= NUM_SAMPLE - 1) || (picks >= SEL_CAP);
      }
      __syncthreads();
      if (sh_stop) break;
      const unsigned long long wkey = sh_bkey;
#pragma unroll
      for (int j = 0; j < 4; ++j) {
        int e = tidx * 4 + j;
        if (pool_key[e] == wkey) {
          sh_px = pool_x[e]; sh_py = pool_y[e]; sh_pz = pool_z[e];
          sel_x[picks] = pool_x[e]; sel_y[picks] = pool_y[e]; sel_z[picks] = pool_z[e];
          pool_key[e] = 0ull;
          if (blockIdx.x == 0) {
            int ptidx = 0x3FFFFF - (int)((wkey >> 10) & 0x3FFFFFull);
            sample_idx[1 + total + picks] = ptidx;
          }
        }
      }
      __syncthreads();
      const float Xp = sh_px, Yp = sh_py, Zp = sh_pz;
#pragma unroll
      for (int j = 0; j < 4; ++j) {
        int e = tidx * 4 + j;
        unsigned long long kv = pool_key[e];
        if (kv) {
          float d2 = d2rn(pool_x[e], pool_y[e], pool_z[e], Xp, Yp, Zp);
          unsigned long long nk = ((unsigned long long)__float_as_uint(d2) << 32) |
                                  (kv & 0xFFFFFFFFull);
          if (nk < kv) pool_key[e] = nk;
        }
      }
      ++picks;
      __syncthreads();
    }
    total += picks;
    sel_cnt = picks;
  }
}

// ---------------- K2a: wave-per-sample KNN + covariance + eigh -> feats9 ----------------
__global__ __launch_bounds__(256) void k2a_knn(
    const float* __restrict__ pos, const float* __restrict__ col,
    const int* __restrict__ sample_idx,
    float4* __restrict__ sp4g, float* __restrict__ feats9) {
  __shared__ float4 sp[NUM_SAMPLE];
  const int tid = threadIdx.x, lane = tid & 63, wv = tid >> 6;
  for (int i = tid; i < NUM_SAMPLE; i += 256) {
    int idx = sample_idx[i];
    float x = pos[3 * idx], y = pos[3 * idx + 1], z = pos[3 * idx + 2];
    float nrm = addrn(addrn(mulrn(x, x), mulrn(y, y)), mulrn(z, z));
    float4 v = make_float4(x, y, z, nrm);
    sp[i] = v;
    if (blockIdx.x == 0) sp4g[i] = v;
  }
  __syncthreads();
  for (int it = 0; it < 4; ++it) {
    const int r = blockIdx.x * 16 + wv * 4 + it;
    float4 pr = sp[r];
    // keys: monotone-mapped f32 d2 (handles tiny-negative self-d2) | index
    unsigned long long kk[16];
#pragma unroll
    for (int k = 0; k < 16; ++k) {
      int j = lane + 64 * k;
      float4 q = sp[j];
      float dot = fmaf(pr.z, q.z, fmaf(pr.y, q.y, mulrn(pr.x, q.x)));
      float d2 = subrn(addrn(pr.w, q.w), mulrn(2.f, dot));
      unsigned b = __float_as_uint(d2);
      unsigned sbits = (b & 0x80000000u) ? ~b : (b | 0x80000000u);
      kk[k] = ((unsigned long long)sbits << 32) | (unsigned)j;
    }
    int bi[17];
#pragma unroll
    for (int rsel = 0; rsel < 17; ++rsel) {
      unsigned long long best = 0xFFFFFFFFFFFFFFFFull;
#pragma unroll
      for (int k = 0; k < 16; ++k) best = (kk[k] < best) ? kk[k] : best;
#pragma unroll
      for (int mk = 1; mk < 64; mk <<= 1) {
        unsigned long long o = (unsigned long long)__shfl_xor((long long)best, mk, 64);
        best = (o < best) ? o : best;
      }
      int j = (int)(best & 0xFFFFFFFFull);
      bi[rsel] = j;
#pragma unroll
      for (int k = 0; k < 16; ++k)
        if (((j >> 6) == k) && ((j & 63) == lane)) kk[k] = 0xFFFFFFFFFFFFFFFFull;
    }
    // mean / covariance over neighbors 1..16 (uniform across lanes)
    float mx = 0.f, my = 0.f, mz = 0.f;
#pragma unroll
    for (int k = 1; k <= 16; ++k) {
      float4 q = sp[bi[k]];
      mx = addrn(mx, q.x); my = addrn(my, q.y); mz = addrn(mz, q.z);
    }
    mx = mulrn(mx, 0.0625f); my = mulrn(my, 0.0625f); mz = mulrn(mz, 0.0625f);
    float c00 = 0.f, c01 = 0.f, c02 = 0.f, c11 = 0.f, c12 = 0.f, c22 = 0.f;
#pragma unroll
    for (int k = 1; k <= 16; ++k) {
      float4 q = sp[bi[k]];
      float dx = subrn(q.x, mx), dy = subrn(q.y, my), dz = subrn(q.z, mz);
      c00 = addrn(c00, mulrn(dx, dx)); c01 = addrn(c01, mulrn(dx, dy));
      c02 = addrn(c02, mulrn(dx, dz)); c11 = addrn(c11, mulrn(dy, dy));
      c12 = addrn(c12, mulrn(dy, dz)); c22 = addrn(c22, mulrn(dz, dz));
    }
    c00 /= 15.f; c01 /= 15.f; c02 /= 15.f; c11 /= 15.f; c12 /= 15.f; c22 /= 15.f;

    float n0, n1, n2;
    eigh3_smallest(c00, c01, c02, c11, c12, c22, n0, n1, n2);
    float nn = __fsqrt_rn(addrn(addrn(mulrn(n0, n0), mulrn(n1, n1)), mulrn(n2, n2)));
    float den = addrn(nn, 1e-8f);
    n0 /= den; n1 /= den; n2 /= den;

    if (lane == 0) {
      int myidx = sample_idx[r];
      float* f = feats9 + r * 9;
      f[0] = pr.x; f[1] = pr.y; f[2] = pr.z;
      f[3] = col[3 * myidx]; f[4] = col[3 * myidx + 1]; f[5] = col[3 * myidx + 2];
      f[6] = n0; f[7] = n1; f[8] = n2;
    }
  }
}

// ---------------- K2b: per-thread MLP (order identical to passing version) ----------------
__global__ __launch_bounds__(64) void k2b_mlp(
    const float* __restrict__ W1, const float* __restrict__ b1,
    const float* __restrict__ W2, const float* __restrict__ b2,
    const float* __restrict__ W3, const float* __restrict__ b3,
    const float* __restrict__ feats9,
    float* __restrict__ featd, int* __restrict__ lbl) {
  __shared__ float hbuf[64][129];
  const int tid = threadIdx.x;
  const int r = blockIdx.x * 64 + tid;
  float f9[9];
#pragma unroll
  for (int k = 0; k < 9; ++k) f9[k] = feats9[r * 9 + k];
  for (int jo = 0; jo < 128; ++jo) {
    float acc = 0.f;
#pragma unroll
    for (int k = 0; k < 9; ++k) acc = fmaf(f9[k], W1[k * 128 + jo], acc);
    acc += b1[jo];
    hbuf[tid][jo] = fmaxf(acc, 0.f);
  }
  float pd[13];
#pragma unroll
  for (int c = 0; c < 13; ++c) pd[c] = 0.f;
  for (int io = 0; io < 128; io += 16) {
    float acc[16];
#pragma unroll
    for (int t = 0; t < 16; ++t) acc[t] = 0.f;
    for (int j = 0; j < 128; ++j) {
      float hj = hbuf[tid][j];
#pragma unroll
      for (int t = 0; t < 16; ++t) acc[t] = fmaf(hj, W2[j * 128 + io + t], acc[t]);
    }
#pragma unroll
    for (int t = 0; t < 16; ++t) {
      float h2 = fmaxf(acc[t] + b2[io + t], 0.f);
#pragma unroll
      for (int c = 0; c < 13; ++c) pd[c] = fmaf(h2, W3[(io + t) * 13 + c], pd[c]);
    }
  }
#pragma unroll
  for (int c = 0; c < 13; ++c) pd[c] += b3[c];
  float mmax = pd[0];
#pragma unroll
  for (int c = 1; c < 13; ++c) mmax = fmaxf(mmax, pd[c]);
  float es = 0.f, ev[13];
#pragma unroll
  for (int c = 0; c < 13; ++c) { ev[c] = expf(pd[c] - mmax); es += ev[c]; }
#pragma unroll
  for (int c = 0; c < 13; ++c) featd[r * 13 + c] = ev[c] / es;
  int am = 0; float bv = pd[0];
#pragma unroll
  for (int c = 1; c < 13; ++c) { if (pd[c] > bv) { bv = pd[c]; am = c; } }
  lbl[r] = am;
}

// ---------------- K3: nearest sample + gather outputs ----------------
__global__ __launch_bounds__(256) void k3_assign(
    const float* __restrict__ pos,
    const float4* __restrict__ sp4g,
    const float* __restrict__ featd,
    const int* __restrict__ lbl,
    float* __restrict__ out) {
  __shared__ float4 sp[NUM_SAMPLE];
  for (int i = threadIdx.x; i < NUM_SAMPLE; i += 256) sp[i] = sp4g[i];
  __syncthreads();
  int i = blockIdx.x * 256 + threadIdx.x;
  float x = pos[3 * i], y = pos[3 * i + 1], z = pos[3 * i + 2];
  float an = addrn(addrn(mulrn(x, x), mulrn(y, y)), mulrn(z, z));
  float bestd = 3.402823466e+38f; int bestj = 0;
#pragma unroll 4
  for (int j = 0; j < NUM_SAMPLE; ++j) {
    float4 q = sp[j];
    float dot = fmaf(z, q.z, fmaf(y, q.y, mulrn(x, q.x)));
    float d2 = subrn(addrn(an, q.w), mulrn(2.f, dot));
    if (d2 < bestd) { bestd = d2; bestj = j; }
  }
  const float* fr = featd + bestj * 13;
  float* o = out + (size_t)i * 13;
#pragma unroll
  for (int c = 0; c < 13; ++c) o[c] = fr[c];
  out[(size_t)N_TOTAL * 13 + i] = (float)lbl[bestj];
}

extern "C" void kernel_launch(void* const* d_in, const int* in_sizes, int n_in,
                              void* d_out, int out_size, void* d_ws, size_t ws_size,
                              hipStream_t stream) {
  (void)in_sizes; (void)n_in; (void)out_size; (void)ws_size;
  const float* pos = (const float*)d_in[0];
  const float* col = (const float*)d_in[1];
  const float* W1 = (const float*)d_in[2];
  const float* b1 = (const float*)d_in[3];
  const float* W2 = (const float*)d_in[4];
  const float* b2 = (const float*)d_in[5];
  const float* W3 = (const float*)d_in[6];
  const float* b3 = (const float*)d_in[7];
  float* out = (float*)d_out;

  char* w = (char*)d_ws;
  unsigned long long* cand = (unsigned long long*)(w);           // 64 KiB
  int* sample_idx = (int*)(w + 65536);                           //  4 KiB
  float4* sp4g = (float4*)(w + 73728);                           // 16 KiB
  float* featd = (float*)(w + 90112);                            // 52 KiB
  int* lbl = (int*)(w + 143360);                                 //  4 KiB
  float* feats9 = (float*)(w + 147456);                          // 36 KiB

  k0_init<<<32, 256, 0, stream>>>(cand, sample_idx);
  k1_fps<<<FPS_BLOCKS, FPS_THREADS, 0, stream>>>(pos, cand, sample_idx);
  k2a_knn<<<64, 256, 0, stream>>>(pos, col, sample_idx, sp4g, feats9);
  k2b_mlp<<<16, 64, 0, stream>>>(W1, b1, W2, b2, W3, b3, feats9, featd, lbl);
  k3_assign<<<N_TOTAL / 256, 256, 0, stream>>>(pos, sp4g, featd, lbl, out);
}